// Round 7
// baseline (41923.615 us; speedup 1.0000x reference)
//
#include <hip/hip_runtime.h>
#include <stdint.h>

typedef unsigned short u16;
typedef unsigned int   u32;
typedef __attribute__((ext_vector_type(8))) short short8;
typedef __attribute__((ext_vector_type(4))) short s16x4;
typedef __attribute__((ext_vector_type(4))) float f32x4;

#define MFMA(a,b,c) __builtin_amdgcn_mfma_f32_16x16x32_bf16((a),(b),(c),0,0,0)
#define NBLK 256

static const int kD = 1024;
static const long kOutB = 256*1024;   // per-batch stride in out/input [64,256,1024]

__device__ __forceinline__ float b2f(u16 v){ union{u32 u; float f;} c; c.u = ((u32)v)<<16; return c.f; }
__device__ __forceinline__ u16 f2b(float f){ union{float f; u32 u;} c; c.f = f; u32 r = c.u + 0x7FFFu + ((c.u>>16)&1u); return (u16)(r>>16); }
__device__ __forceinline__ float fexp2(float x){ return __builtin_amdgcn_exp2f(x); }
__device__ __forceinline__ float frcp(float x){ return __builtin_amdgcn_rcpf(x); }
__device__ __forceinline__ float tanh_(float x){ float e = fexp2(x*2.885390081777927f); return 1.f - 2.f*frcp(e+1.f); }
__device__ __forceinline__ float sigm_(float x){ return frcp(1.f + fexp2(-1.4426950408889634f*x)); }

// ---- JAX partitionable Threefry-2x32, key(1)=(0,1), ctr=(0,j), fold o0^o1 ----
__host__ __device__ __forceinline__ u32 rotl32_(u32 x, int r){ return (x << r) | (x >> (32 - r)); }
__host__ __device__ bool tf_bit(u32 j){
    const u32 k0 = 0u, k1 = 1u, k2 = 0x1BD11BDAu ^ 0u ^ 1u;
    const int R0[4] = {13,15,26,6}, R1[4] = {17,29,16,24};
    u32 x0 = 0u, x1 = j;
    x0 += k0; x1 += k1;
    for(int i=0;i<4;i++){ x0 += x1; x1 = rotl32_(x1,R0[i]); x1 ^= x0; }
    x0 += k1; x1 += k2 + 1u;
    for(int i=0;i<4;i++){ x0 += x1; x1 = rotl32_(x1,R1[i]); x1 ^= x0; }
    x0 += k2; x1 += k0 + 2u;
    for(int i=0;i<4;i++){ x0 += x1; x1 = rotl32_(x1,R0[i]); x1 ^= x0; }
    x0 += k0; x1 += k1 + 3u;
    for(int i=0;i<4;i++){ x0 += x1; x1 = rotl32_(x1,R1[i]); x1 ^= x0; }
    x0 += k1; x1 += k2 + 4u;
    for(int i=0;i<4;i++){ x0 += x1; x1 = rotl32_(x1,R0[i]); x1 ^= x0; }
    x0 += k2; x1 += k0 + 5u;
    return (((x0 ^ x1) >> 31) == 0u);
}

// ---- grid barrier: relaxed agent atomics + __threadfence (wbl2/inv) ----
__device__ __forceinline__ void gridbar(u32* cnt, u32* gen){
    __syncthreads();
    if(threadIdx.x == 0){
        __threadfence();   // release: flush this block's writes past L2
        u32 g = __hip_atomic_load(gen, __ATOMIC_RELAXED, __HIP_MEMORY_SCOPE_AGENT);
        u32 a = __hip_atomic_fetch_add(cnt, 1u, __ATOMIC_RELAXED, __HIP_MEMORY_SCOPE_AGENT);
        if(a == NBLK - 1u){
            __hip_atomic_store(cnt, 0u, __ATOMIC_RELAXED, __HIP_MEMORY_SCOPE_AGENT);
            __threadfence();
            __hip_atomic_store(gen, g + 1u, __ATOMIC_RELAXED, __HIP_MEMORY_SCOPE_AGENT);
        } else {
            while(__hip_atomic_load(gen, __ATOMIC_RELAXED, __HIP_MEMORY_SCOPE_AGENT) == g)
                __builtin_amdgcn_s_sleep(2);
        }
        __threadfence();   // acquire: invalidate stale L1/L2 lines
    }
    __syncthreads();
}

// ---- f32 -> bf16 convert (grid-stride) ----
__global__ void k_cvt(const float* __restrict__ in, u16* __restrict__ out, int n){
    int i = blockIdx.x*blockDim.x + threadIdx.x;
    int st = gridDim.x*blockDim.x;
    for(; i < n; i += st) out[i] = f2b(in[i]);
}

// ---- transpose + convert: in [R][C] f32 -> out [C][R] bf16 ----
__global__ void k_cvt_t(const float* __restrict__ in, u16* __restrict__ out, int R, int C){
    __shared__ float tile[32][33];
    int bx = blockIdx.x, by = blockIdx.y;
    int tx = threadIdx.x, ty = threadIdx.y;   // 32 x 8
    for(int j = 0; j < 32; j += 8) tile[ty+j][tx] = in[(by*32+ty+j)*C + bx*32+tx];
    __syncthreads();
    for(int j = 0; j < 32; j += 8) out[(bx*32+ty+j)*R + by*32+tx] = f2b(tile[tx][ty+j]);
}

// ---- init: h0 (f32 + bf16) from hidden^T; outs[:,0,:] = input row 0; zero sync cells ----
__global__ void k_init(const float* __restrict__ hidden, const float* __restrict__ input,
                       float* __restrict__ h0f, u16* __restrict__ h0b, float* __restrict__ out,
                       u32* __restrict__ sync){
    int i = blockIdx.x*blockDim.x + threadIdx.x;   // 65536
    int b = i >> 10, d = i & 1023;
    float h = hidden[d*64 + b];
    h0f[i] = h; h0b[i] = f2b(h);
    out[(long)b*kOutB + d] = input[(long)b*kOutB + d];
    if(i < 2) sync[i] = 0u;
}

// ---- enc_proj = encb [16384,1024] @ wencT (N,K) -> epb bf16 (one-time) ----
__global__ __launch_bounds__(256) void k_gemm_ep(const u16* __restrict__ A, const u16* __restrict__ BT,
                                                 u16* __restrict__ Cb){
    int m0 = blockIdx.x*64, n0 = blockIdx.y*64;
    int w = threadIdx.x >> 6, l = threadIdx.x & 63;
    int r0 = l & 15, kh = (l >> 4) * 8;
    const u16* arow = A + (long)(m0 + w*16 + r0)*1024 + kh;
    f32x4 acc[4] = {};
    for(int k0 = 0; k0 < 1024; k0 += 32){
        short8 a = *(const short8*)(arow + k0);
        #pragma unroll
        for(int j = 0; j < 4; ++j){
            short8 b = *(const short8*)(BT + (long)(n0 + j*16 + r0)*1024 + k0 + kh);
            acc[j] = MFMA(a, b, acc[j]);
        }
    }
    int orow = m0 + w*16 + (l>>4)*4;
    int ocol = n0 + (l & 15);
    #pragma unroll
    for(int j = 0; j < 4; ++j)
        #pragma unroll
        for(int r = 0; r < 4; ++r)
            Cb[(long)(orow + r)*1024 + ocol + j*16] = f2b(acc[j][r]);
}

// ================= persistent step kernel: 255 steps, 4 phases/step =================
__global__ __launch_bounds__(256, 1) void k_steps(
        const u16* __restrict__ epb, const u16* __restrict__ inb, const u16* __restrict__ encb,
        const u16* __restrict__ wihb, const u16* __restrict__ whhb, const u16* __restrict__ wdecT,
        const float* __restrict__ bih, const float* __restrict__ bhh,
        const float* __restrict__ vv, const int* __restrict__ lengths,
        float* __restrict__ hWp, float* __restrict__ eny, u16* __restrict__ ctxb,
        float* __restrict__ hf0, float* __restrict__ hf1,
        u16* __restrict__ hb0, u16* __restrict__ hb1,
        float* __restrict__ out, u32* __restrict__ sync){
    __shared__ float sA[1024];
    __shared__ float sB[1024];
    __shared__ float sRed[8];
    u32* cnt = sync; u32* gen = sync + 1;

    const int bid = blockIdx.x, tid = threadIdx.x;
    const int w = tid >> 6, l = tid & 63;
    const int r0 = l & 15, kh = (l >> 4) * 8;

    // ---- hoisted per-block constants ----
    // P1 (hW k-split): ks = bid&3, n-chunk = bid>>2
    const int p1_ks = bid & 3, p1_n0 = (bid >> 2) * 16, p1_kb = p1_ks * 256;
    const u16* p1_brow = wdecT + (long)(p1_n0 + r0)*1024 + p1_kb + kh;
    const long p1_aoff = (long)(w*16 + r0)*1024 + p1_kb + kh;
    float* p1_dst = hWp + p1_ks*65536 + (w*16 + (l>>4)*4)*1024 + p1_n0 + (l & 15);
    // P2 (energy): b = bid>>2, sq = bid&3
    const int p2_b = bid >> 2, p2_sq = bid & 3;
    const int p2_len = lengths[p2_b];
    float rv[16];
    #pragma unroll
    for(int j = 0; j < 16; ++j) rv[j] = vv[l*16 + j];
    const u16* p2_ep = epb + ((long)(p2_b*256 + p2_sq*64 + w*16))*1024 + l*16;
    // P3 (ctx): b = bid>>2, dq = bid&3
    const u16* p3_eb = encb + (long)p2_b*262144 + p2_sq*256 + l*4;   // dq == p2_sq slot reuse
    // P4 (GRU): active for bid < 64
    const int u0 = bid * 16;
    const int ucol = u0 + (l & 15);
    const u16 *g_wr=0,*g_wz=0,*g_wn=0,*g_vr=0,*g_vz=0,*g_vn=0,*g_ctx=0,*g_h0=0,*g_h1=0,*g_in=0;
    float bir=0,biz=0,bin_=0,bhr=0,bhz=0,bhn=0;
    if(bid < 64){
        g_wr = wihb + (long)(       u0 + r0)*2048 + kh;
        g_wz = wihb + (long)(1024 + u0 + r0)*2048 + kh;
        g_wn = wihb + (long)(2048 + u0 + r0)*2048 + kh;
        g_vr = whhb + (long)(       u0 + r0)*1024 + kh;
        g_vz = whhb + (long)(1024 + u0 + r0)*1024 + kh;
        g_vn = whhb + (long)(2048 + u0 + r0)*1024 + kh;
        g_ctx = ctxb + (w*16 + r0)*1024 + kh;
        g_h0  = hb0  + (w*16 + r0)*1024 + kh;
        g_h1  = hb1  + (w*16 + r0)*1024 + kh;
        g_in  = inb  + (long)(w*16 + r0)*kOutB + kh;
        bir = bih[ucol]; biz = bih[1024+ucol]; bin_ = bih[2048+ucol];
        bhr = bhh[ucol]; bhz = bhh[1024+ucol]; bhn  = bhh[2048+ucol];
    }

    for(int t = 1; t < 256; ++t){
        const bool odd = (t & 1);
        const u16* hbo = odd ? hb0 : hb1;
        // ---- P1: hWp[ks][64][1024] = hb[64, kslice] @ wdecT ----
        {
            const u16* arow = hbo + p1_aoff;
            f32x4 acc = {};
            #pragma unroll
            for(int k0 = 0; k0 < 256; k0 += 32)
                acc = MFMA(*(const short8*)(arow + k0), *(const short8*)(p1_brow + k0), acc);
            #pragma unroll
            for(int r = 0; r < 4; ++r) p1_dst[r*1024] = acc[r];
        }
        gridbar(cnt, gen);
        // ---- P2: energy[b, s-quarter] ----
        {
            float rh[16];
            #pragma unroll
            for(int j4 = 0; j4 < 4; ++j4){
                f32x4 s0 = *(const f32x4*)(hWp +            p2_b*1024 + l*16 + j4*4);
                s0 += *(const f32x4*)(hWp +  65536 + p2_b*1024 + l*16 + j4*4);
                s0 += *(const f32x4*)(hWp + 131072 + p2_b*1024 + l*16 + j4*4);
                s0 += *(const f32x4*)(hWp + 196608 + p2_b*1024 + l*16 + j4*4);
                rh[j4*4+0] = s0.x; rh[j4*4+1] = s0.y; rh[j4*4+2] = s0.z; rh[j4*4+3] = s0.w;
            }
            for(int si = 0; si < 16; ++si){
                int s = p2_sq*64 + w*16 + si;
                const u16* row = p2_ep + (long)si*1024;
                short8 q0 = *(const short8*)(row);
                short8 q1 = *(const short8*)(row + 8);
                float acc = 0.f;
                #pragma unroll
                for(int j = 0; j < 8; ++j) acc += rv[j]   * tanh_(b2f((u16)q0[j]) + rh[j]);
                #pragma unroll
                for(int j = 0; j < 8; ++j) acc += rv[8+j] * tanh_(b2f((u16)q1[j]) + rh[8+j]);
                #pragma unroll
                for(int off = 32; off; off >>= 1) acc += __shfl_xor(acc, off);
                if(l == 0) eny[p2_b*256 + s] = (s < p2_len) ? acc : -1e9f;
            }
        }
        gridbar(cnt, gen);
        // ---- P3: softmax + ctx[b, d-quarter] ----
        {
            float e = eny[p2_b*256 + tid];
            float m = e;
            #pragma unroll
            for(int off = 32; off; off >>= 1) m = fmaxf(m, __shfl_xor(m, off));
            if((tid & 63) == 0) sRed[tid >> 6] = m;
            __syncthreads();
            m = fmaxf(fmaxf(sRed[0], sRed[1]), fmaxf(sRed[2], sRed[3]));
            float pp = fexp2((e - m)*1.4426950408889634f);
            sA[tid] = pp;
            float sm = pp;
            #pragma unroll
            for(int off = 32; off; off >>= 1) sm += __shfl_xor(sm, off);
            if((tid & 63) == 0) sRed[4 + (tid >> 6)] = sm;
            __syncthreads();
            float inv = 1.f / (sRed[4] + sRed[5] + sRed[6] + sRed[7]);
            float a0=0.f, a1=0.f, a2=0.f, a3=0.f;
            #pragma unroll 4
            for(int si = 0; si < 64; ++si){
                int s = w*64 + si;
                float ps = sA[s];
                s16x4 q = *(const s16x4*)(p3_eb + (long)s*1024);
                a0 += ps*b2f((u16)q[0]); a1 += ps*b2f((u16)q[1]);
                a2 += ps*b2f((u16)q[2]); a3 += ps*b2f((u16)q[3]);
            }
            sB[w*256 + l*4+0] = a0; sB[w*256 + l*4+1] = a1;
            sB[w*256 + l*4+2] = a2; sB[w*256 + l*4+3] = a3;
            __syncthreads();
            float c = (sB[tid] + sB[256+tid] + sB[512+tid] + sB[768+tid]) * inv;
            ctxb[p2_b*1024 + p2_sq*256 + tid] = f2b(c);
        }
        gridbar(cnt, gen);
        // ---- P4: fused GRU (64 blocks) ----
        if(bid < 64){
            const float* hfo = odd ? hf0 : hf1;
            float* hfn = odd ? hf1 : hf0;
            u16* hbn = odd ? hb1 : hb0;
            bool useTeach = (t == 1) || tf_bit((u32)(t - 1));
            const u16* hrow = odd ? g_h0 : g_h1;
            const u16* selrow = useTeach ? (g_in + (long)(t - 1)*1024) : hrow;
            f32x4 air = {}, aiz = {}, ain = {}, ahr = {}, ahz = {}, ahn = {};
            for(int k0 = 0; k0 < 1024; k0 += 32){
                short8 a = *(const short8*)(selrow + k0);
                air = MFMA(a, *(const short8*)(g_wr + k0), air);
                aiz = MFMA(a, *(const short8*)(g_wz + k0), aiz);
                ain = MFMA(a, *(const short8*)(g_wn + k0), ain);
                short8 h = *(const short8*)(hrow + k0);
                ahr = MFMA(h, *(const short8*)(g_vr + k0), ahr);
                ahz = MFMA(h, *(const short8*)(g_vz + k0), ahz);
                ahn = MFMA(h, *(const short8*)(g_vn + k0), ahn);
            }
            for(int k0 = 0; k0 < 1024; k0 += 32){
                short8 a = *(const short8*)(g_ctx + k0);
                air = MFMA(a, *(const short8*)(g_wr + 1024 + k0), air);
                aiz = MFMA(a, *(const short8*)(g_wz + 1024 + k0), aiz);
                ain = MFMA(a, *(const short8*)(g_wn + 1024 + k0), ain);
            }
            int row = w*16 + (l>>4)*4;
            #pragma unroll
            for(int r = 0; r < 4; ++r){
                int b = row + r;
                float rg = sigm_(air[r] + bir + ahr[r] + bhr);
                float z  = sigm_(aiz[r] + biz + ahz[r] + bhz);
                float n  = tanh_(ain[r] + bin_ + rg*(ahn[r] + bhn));
                float hold = hfo[b*1024 + ucol];
                float hn = (1.f - z)*n + z*hold;
                hfn[b*1024 + ucol] = hn;
                hbn[b*1024 + ucol] = f2b(hn);
                out[(long)b*kOutB + (long)t*1024 + ucol] = hn;
            }
        }
        gridbar(cnt, gen);
    }
}

extern "C" void kernel_launch(void* const* d_in, const int* in_sizes, int n_in,
                              void* d_out, int out_size, void* d_ws, size_t ws_size,
                              hipStream_t stream){
    (void)in_sizes; (void)n_in; (void)out_size;
    const float* input    = (const float*)d_in[0];   // [64,256,1024]
    const float* hidden   = (const float*)d_in[1];   // [1024,64]
    const float* enc_outs = (const float*)d_in[2];   // [64,256,1024]
    const int*   lengths  = (const int*)  d_in[3];   // [64]
    const float* W_enc    = (const float*)d_in[4];   // [1024,1024] (K,N)
    const float* W_dec    = (const float*)d_in[5];   // [1024,1024] (K,N)
    const float* v        = (const float*)d_in[6];   // [1024]
    const float* W_ih     = (const float*)d_in[7];   // [3072,2048] (N,K)
    const float* W_hh     = (const float*)d_in[8];   // [3072,1024] (N,K)
    const float* b_ih     = (const float*)d_in[9];
    const float* b_hh     = (const float*)d_in[10];
    float* out = (float*)d_out;                      // [64,256,1024]

    // ---- workspace carve (~118 MB) ----
    char* p = (char*)d_ws;
    auto alloc = [&](size_t bytes){ void* r = (void*)p; p += (bytes + 255) & ~(size_t)255; return r; };
    u16* epb   = (u16*)alloc((size_t)16384*1024*2);   // enc_proj bf16
    u16* inb   = (u16*)alloc((size_t)16384*1024*2);   // input bf16
    u16* encb  = (u16*)alloc((size_t)16384*1024*2);   // encoder_outs bf16
    u16* wihb  = (u16*)alloc((size_t)3072*2048*2);
    u16* whhb  = (u16*)alloc((size_t)3072*1024*2);
    u16* wencT = (u16*)alloc((size_t)1024*1024*2);
    u16* wdecT = (u16*)alloc((size_t)1024*1024*2);
    float* hf0 = (float*)alloc((size_t)64*1024*4);
    float* hf1 = (float*)alloc((size_t)64*1024*4);
    u16* hb0   = (u16*)alloc((size_t)64*1024*2);
    u16* hb1   = (u16*)alloc((size_t)64*1024*2);
    float* hWp = (float*)alloc((size_t)4*64*1024*4);  // hW K-split partials
    float* eny = (float*)alloc((size_t)64*256*4);
    u16* ctxb  = (u16*)alloc((size_t)64*1024*2);
    u32* sync  = (u32*)alloc(256);
    if((size_t)(p - (char*)d_ws) > ws_size) return;

    // ---- one-time prep ----
    k_cvt<<<2048, 256, 0, stream>>>(enc_outs, encb, 16384*1024);
    k_cvt<<<2048, 256, 0, stream>>>(input,    inb,  16384*1024);
    k_cvt<<<1024, 256, 0, stream>>>(W_ih,     wihb, 3072*2048);
    k_cvt<<<512,  256, 0, stream>>>(W_hh,     whhb, 3072*1024);
    k_cvt_t<<<dim3(32,32), dim3(32,8), 0, stream>>>(W_enc, wencT, 1024, 1024);
    k_cvt_t<<<dim3(32,32), dim3(32,8), 0, stream>>>(W_dec, wdecT, 1024, 1024);
    k_init<<<256, 256, 0, stream>>>(hidden, input, hf0, hb0, out, sync);
    k_gemm_ep<<<dim3(256,16), 256, 0, stream>>>(encb, wencT, epb);

    // ---- all 255 steps in one persistent kernel ----
    k_steps<<<NBLK, 256, 0, stream>>>(epb, inb, encb, wihb, whhb, wdecT,
                                      b_ih, b_hh, v, lengths,
                                      hWp, eny, ctxb, hf0, hf1, hb0, hb1,
                                      out, sync);
}

// Round 8
// 29777.887 us; speedup vs baseline: 1.4079x; 1.4079x over previous
//
#include <hip/hip_runtime.h>
#include <stdint.h>

typedef unsigned short u16;
typedef unsigned int   u32;
typedef unsigned long long u64;
typedef __attribute__((ext_vector_type(8))) short short8;
typedef __attribute__((ext_vector_type(4))) short s16x4;
typedef __attribute__((ext_vector_type(4))) float f32x4;

#define MFMA(a,b,c) __builtin_amdgcn_mfma_f32_16x16x32_bf16((a),(b),(c),0,0,0)
#define NBLK 256

static const int kD = 1024;
static const long kOutB = 256*1024;   // per-batch stride in out/input [64,256,1024]

__device__ __forceinline__ float b2f(u16 v){ union{u32 u; float f;} c; c.u = ((u32)v)<<16; return c.f; }
__device__ __forceinline__ u16 f2b(float f){ union{float f; u32 u;} c; c.f = f; u32 r = c.u + 0x7FFFu + ((c.u>>16)&1u); return (u16)(r>>16); }
__device__ __forceinline__ float fexp2(float x){ return __builtin_amdgcn_exp2f(x); }
__device__ __forceinline__ float frcp(float x){ return __builtin_amdgcn_rcpf(x); }
__device__ __forceinline__ float tanh_(float x){ float e = fexp2(x*2.885390081777927f); return 1.f - 2.f*frcp(e+1.f); }
__device__ __forceinline__ float sigm_(float x){ return frcp(1.f + fexp2(-1.4426950408889634f*x)); }

// ---- coherent (L2-bypassing, sc1) accessors for cross-XCD communication data ----
__device__ __forceinline__ u64 ald64(const void* p){
    return __hip_atomic_load((const u64*)p, __ATOMIC_RELAXED, __HIP_MEMORY_SCOPE_AGENT);
}
__device__ __forceinline__ u32 ald32(const void* p){
    return __hip_atomic_load((const u32*)p, __ATOMIC_RELAXED, __HIP_MEMORY_SCOPE_AGENT);
}
__device__ __forceinline__ void ast64(void* p, u64 v){
    __hip_atomic_store((u64*)p, v, __ATOMIC_RELAXED, __HIP_MEMORY_SCOPE_AGENT);
}
__device__ __forceinline__ void ast32(void* p, u32 v){
    __hip_atomic_store((u32*)p, v, __ATOMIC_RELAXED, __HIP_MEMORY_SCOPE_AGENT);
}
__device__ __forceinline__ short8 ald_s8(const u16* p){
    union{ u64 q[2]; short8 v; } u;
    u.q[0] = ald64(p);
    u.q[1] = ald64(p + 4);
    return u.v;
}

// ---- JAX partitionable Threefry-2x32, key(1)=(0,1), ctr=(0,j), fold o0^o1 ----
__device__ __forceinline__ u32 rotl32_(u32 x, int r){ return (x << r) | (x >> (32 - r)); }
__device__ bool tf_bit(u32 j){
    const u32 k0 = 0u, k1 = 1u, k2 = 0x1BD11BDAu ^ 0u ^ 1u;
    const int R0[4] = {13,15,26,6}, R1[4] = {17,29,16,24};
    u32 x0 = 0u, x1 = j;
    x0 += k0; x1 += k1;
    for(int i=0;i<4;i++){ x0 += x1; x1 = rotl32_(x1,R0[i]); x1 ^= x0; }
    x0 += k1; x1 += k2 + 1u;
    for(int i=0;i<4;i++){ x0 += x1; x1 = rotl32_(x1,R1[i]); x1 ^= x0; }
    x0 += k2; x1 += k0 + 2u;
    for(int i=0;i<4;i++){ x0 += x1; x1 = rotl32_(x1,R0[i]); x1 ^= x0; }
    x0 += k0; x1 += k1 + 3u;
    for(int i=0;i<4;i++){ x0 += x1; x1 = rotl32_(x1,R1[i]); x1 ^= x0; }
    x0 += k1; x1 += k2 + 4u;
    for(int i=0;i<4;i++){ x0 += x1; x1 = rotl32_(x1,R0[i]); x1 ^= x0; }
    x0 += k2; x1 += k0 + 5u;
    return (((x0 ^ x1) >> 31) == 0u);
}

// ---- grid barrier: NO cache invalidation. sc1 write-through stores + vmcnt drain
//      give visibility; arrive/spin with relaxed agent atomics. cnt/gen 256B apart. ----
__device__ __forceinline__ void gridbar(u32* cnt, u32* gen){
    asm volatile("s_waitcnt vmcnt(0)" ::: "memory");   // all waves: drain sc1 stores
    __syncthreads();
    if(threadIdx.x == 0){
        u32 g = __hip_atomic_load(gen, __ATOMIC_RELAXED, __HIP_MEMORY_SCOPE_AGENT);
        u32 a = __hip_atomic_fetch_add(cnt, 1u, __ATOMIC_RELAXED, __HIP_MEMORY_SCOPE_AGENT);
        if(a == NBLK - 1u){
            __hip_atomic_store(cnt, 0u, __ATOMIC_RELAXED, __HIP_MEMORY_SCOPE_AGENT);
            asm volatile("s_waitcnt vmcnt(0)" ::: "memory");   // cnt reset visible before gen bump
            __hip_atomic_store(gen, g + 1u, __ATOMIC_RELAXED, __HIP_MEMORY_SCOPE_AGENT);
        } else {
            while(__hip_atomic_load(gen, __ATOMIC_RELAXED, __HIP_MEMORY_SCOPE_AGENT) == g)
                __builtin_amdgcn_s_sleep(1);
        }
    }
    __syncthreads();
}

// ---- f32 -> bf16 convert (grid-stride) ----
__global__ void k_cvt(const float* __restrict__ in, u16* __restrict__ out, int n){
    int i = blockIdx.x*blockDim.x + threadIdx.x;
    int st = gridDim.x*blockDim.x;
    for(; i < n; i += st) out[i] = f2b(in[i]);
}

// ---- transpose + convert: in [R][C] f32 -> out [C][R] bf16 ----
__global__ void k_cvt_t(const float* __restrict__ in, u16* __restrict__ out, int R, int C){
    __shared__ float tile[32][33];
    int bx = blockIdx.x, by = blockIdx.y;
    int tx = threadIdx.x, ty = threadIdx.y;   // 32 x 8
    for(int j = 0; j < 32; j += 8) tile[ty+j][tx] = in[(by*32+ty+j)*C + bx*32+tx];
    __syncthreads();
    for(int j = 0; j < 32; j += 8) out[(bx*32+ty+j)*R + by*32+tx] = f2b(tile[tx][ty+j]);
}

// ---- init: h0 (f32 + bf16) from hidden^T; outs[:,0,:] = input row 0; zero sync ----
__global__ void k_init(const float* __restrict__ hidden, const float* __restrict__ input,
                       float* __restrict__ h0f, u16* __restrict__ h0b, float* __restrict__ out,
                       u32* __restrict__ sync){
    int i = blockIdx.x*blockDim.x + threadIdx.x;   // 65536
    int b = i >> 10, d = i & 1023;
    float h = hidden[d*64 + b];
    h0f[i] = h; h0b[i] = f2b(h);
    out[(long)b*kOutB + d] = input[(long)b*kOutB + d];
    if(i < 128) sync[i] = 0u;
}

// ---- enc_proj = encb [16384,1024] @ wencT (N,K) -> epb bf16 (one-time) ----
__global__ __launch_bounds__(256) void k_gemm_ep(const u16* __restrict__ A, const u16* __restrict__ BT,
                                                 u16* __restrict__ Cb){
    int m0 = blockIdx.x*64, n0 = blockIdx.y*64;
    int w = threadIdx.x >> 6, l = threadIdx.x & 63;
    int r0 = l & 15, kh = (l >> 4) * 8;
    const u16* arow = A + (long)(m0 + w*16 + r0)*1024 + kh;
    f32x4 acc[4] = {};
    for(int k0 = 0; k0 < 1024; k0 += 32){
        short8 a = *(const short8*)(arow + k0);
        #pragma unroll
        for(int j = 0; j < 4; ++j){
            short8 b = *(const short8*)(BT + (long)(n0 + j*16 + r0)*1024 + k0 + kh);
            acc[j] = MFMA(a, b, acc[j]);
        }
    }
    int orow = m0 + w*16 + (l>>4)*4;
    int ocol = n0 + (l & 15);
    #pragma unroll
    for(int j = 0; j < 4; ++j)
        #pragma unroll
        for(int r = 0; r < 4; ++r)
            Cb[(long)(orow + r)*1024 + ocol + j*16] = f2b(acc[j][r]);
}

// ================= persistent step kernel: 255 steps, 4 phases/step =================
__global__ __launch_bounds__(256, 1) void k_steps(
        const u16* __restrict__ epb, const u16* __restrict__ inb, const u16* __restrict__ encb,
        const u16* __restrict__ wihb, const u16* __restrict__ whhb, const u16* __restrict__ wdecT,
        const float* __restrict__ bih, const float* __restrict__ bhh,
        const float* __restrict__ vv, const int* __restrict__ lengths,
        float* __restrict__ hWp, float* __restrict__ eny, u16* __restrict__ ctxb,
        const float* __restrict__ hf0,
        u16* __restrict__ hb0, u16* __restrict__ hb1,
        float* __restrict__ out, u32* __restrict__ sync){
    __shared__ float sA[1024];
    __shared__ float sB[1024];
    __shared__ float sRed[8];
    u32* cnt = sync; u32* gen = sync + 64;

    const int bid = blockIdx.x, tid = threadIdx.x;
    const int w = tid >> 6, l = tid & 63;
    const int r0 = l & 15, kh = (l >> 4) * 8;

    // ---- P1 constants: hW k-split, ks = bid&3, 16-col chunk = bid>>2 ----
    const int p1_ks = bid & 3, p1_n0 = (bid >> 2) * 16, p1_kb = p1_ks * 256;
    const u16* p1_brow = wdecT + (long)(p1_n0 + r0)*1024 + p1_kb + kh;
    const long p1_aoff = (long)(w*16 + r0)*1024 + p1_kb + kh;
    const int p1_mrow = w*16 + (l>>4)*4;
    const int p1_dcol = p1_n0 + (l & 15);
    // ---- P2 constants: b = bid>>2, sq = bid&3 ----
    const int p2_b = bid >> 2, p2_sq = bid & 3;
    const int p2_len = lengths[p2_b];
    float rv[16];
    #pragma unroll
    for(int j = 0; j < 16; ++j) rv[j] = vv[l*16 + j];
    const u16* p2_ep = epb + ((long)(p2_b*256 + p2_sq*64 + w*16))*1024 + l*16;
    // ---- P3 constants (dq == p2_sq) ----
    const u16* p3_eb = encb + (long)p2_b*262144 + p2_sq*256 + l*4;
    // ---- P4 constants: active for bid < 64, u-cols u0..u0+15 ----
    const int u0 = bid * 16;
    const int ucol = u0 + (l & 15);
    const int p4_row = w*16 + (l>>4)*4;
    const u16 *g_wr=0,*g_wz=0,*g_wn=0,*g_vr=0,*g_vz=0,*g_vn=0;
    long ctx_off=0, h_off=0; const u16* g_in=0;
    float bir=0,biz=0,bin_=0,bhr=0,bhz=0,bhn=0;
    float hold[4] = {0.f,0.f,0.f,0.f};
    if(bid < 64){
        g_wr = wihb + (long)(       u0 + r0)*2048 + kh;
        g_wz = wihb + (long)(1024 + u0 + r0)*2048 + kh;
        g_wn = wihb + (long)(2048 + u0 + r0)*2048 + kh;
        g_vr = whhb + (long)(       u0 + r0)*1024 + kh;
        g_vz = whhb + (long)(1024 + u0 + r0)*1024 + kh;
        g_vn = whhb + (long)(2048 + u0 + r0)*1024 + kh;
        ctx_off = (long)(w*16 + r0)*1024 + kh;
        h_off   = ctx_off;
        g_in    = inb + (long)(w*16 + r0)*kOutB + kh;
        bir = bih[ucol]; biz = bih[1024+ucol]; bin_ = bih[2048+ucol];
        bhr = bhh[ucol]; bhz = bhh[1024+ucol]; bhn  = bhh[2048+ucol];
        #pragma unroll
        for(int r = 0; r < 4; ++r) hold[r] = hf0[(p4_row + r)*1024 + ucol];   // h master in regs
    }

    for(int t = 1; t < 256; ++t){
        const bool odd = (t & 1);
        const u16* hbo = odd ? hb0 : hb1;   // h_{t-1} bf16
        u16*       hbn = odd ? hb1 : hb0;   // h_t bf16
        // ---- P1: hWp[ks][64][1024] = hb[64, k-slice] @ wdecT (sc1 in/out) ----
        {
            const u16* arow = hbo + p1_aoff;
            f32x4 acc = {};
            #pragma unroll
            for(int k0 = 0; k0 < 256; k0 += 32)
                acc = MFMA(ald_s8(arow + k0), *(const short8*)(p1_brow + k0), acc);
            #pragma unroll
            for(int r = 0; r < 4; ++r){
                float mine = acc[r];
                float oth = __shfl_xor(mine, 1);
                if(!(l & 1)){
                    union{ float f[2]; u64 q; } pk; pk.f[0] = mine; pk.f[1] = oth;
                    ast64(hWp + p1_ks*65536 + (p1_mrow + r)*1024 + p1_dcol, pk.q);
                }
            }
        }
        gridbar(cnt, gen);
        // ---- P2: energy[b, s-quarter] (hWp sc1; ep nontemporal so weights stay L2-hot) ----
        {
            float rh[16];
            #pragma unroll
            for(int j = 0; j < 16; ++j) rh[j] = 0.f;
            #pragma unroll
            for(int ks = 0; ks < 4; ++ks){
                const float* hp = hWp + ks*65536 + p2_b*1024 + l*16;
                #pragma unroll
                for(int j = 0; j < 8; ++j){
                    union{ u64 q; float f[2]; } uu; uu.q = ald64(hp + j*2);
                    rh[2*j]   += uu.f[0];
                    rh[2*j+1] += uu.f[1];
                }
            }
            for(int si = 0; si < 16; ++si){
                int s = p2_sq*64 + w*16 + si;
                const u16* row = p2_ep + (long)si*1024;
                short8 q0 = __builtin_nontemporal_load((const short8*)(row));
                short8 q1 = __builtin_nontemporal_load((const short8*)(row + 8));
                float acc = 0.f;
                #pragma unroll
                for(int j = 0; j < 8; ++j) acc += rv[j]   * tanh_(b2f((u16)q0[j]) + rh[j]);
                #pragma unroll
                for(int j = 0; j < 8; ++j) acc += rv[8+j] * tanh_(b2f((u16)q1[j]) + rh[8+j]);
                #pragma unroll
                for(int off = 32; off; off >>= 1) acc += __shfl_xor(acc, off);
                if(l == 0){
                    float val = (s < p2_len) ? acc : -1e9f;
                    ast32(eny + p2_b*256 + s, __float_as_uint(val));
                }
            }
        }
        gridbar(cnt, gen);
        // ---- P3: softmax + ctx[b, d-quarter] (eny sc1 in, ctx sc1 out, enc nontemporal) ----
        {
            float e = __uint_as_float(ald32(eny + p2_b*256 + tid));
            float m = e;
            #pragma unroll
            for(int off = 32; off; off >>= 1) m = fmaxf(m, __shfl_xor(m, off));
            if((tid & 63) == 0) sRed[tid >> 6] = m;
            __syncthreads();
            m = fmaxf(fmaxf(sRed[0], sRed[1]), fmaxf(sRed[2], sRed[3]));
            float pp = fexp2((e - m)*1.4426950408889634f);
            sA[tid] = pp;
            float sm = pp;
            #pragma unroll
            for(int off = 32; off; off >>= 1) sm += __shfl_xor(sm, off);
            if((tid & 63) == 0) sRed[4 + (tid >> 6)] = sm;
            __syncthreads();
            float inv = 1.f / (sRed[4] + sRed[5] + sRed[6] + sRed[7]);
            float a0=0.f, a1=0.f, a2=0.f, a3=0.f;
            #pragma unroll 4
            for(int si = 0; si < 64; ++si){
                int s = w*64 + si;
                float ps = sA[s];
                s16x4 q = __builtin_nontemporal_load((const s16x4*)(p3_eb + (long)s*1024));
                a0 += ps*b2f((u16)q[0]); a1 += ps*b2f((u16)q[1]);
                a2 += ps*b2f((u16)q[2]); a3 += ps*b2f((u16)q[3]);
            }
            sB[w*256 + l*4+0] = a0; sB[w*256 + l*4+1] = a1;
            sB[w*256 + l*4+2] = a2; sB[w*256 + l*4+3] = a3;
            __syncthreads();
            float c = (sB[tid] + sB[256+tid] + sB[512+tid] + sB[768+tid]) * inv;
            u32 cb = (u32)f2b(c);
            u32 ob = (u32)__shfl_xor((int)cb, 1);
            if(!(tid & 1))
                ast32((u32*)ctxb + ((p2_b*1024 + p2_sq*256 + tid) >> 1), cb | (ob << 16));
        }
        gridbar(cnt, gen);
        // ---- P4: fused GRU (64 blocks); A-panels via sc1, weights L2-cached, h in regs ----
        if(bid < 64){
            bool useTeach = (t == 1) || tf_bit((u32)(t - 1));
            const u16* hrow = hbo + h_off;
            const u16* selrow = useTeach ? (g_in + (long)(t - 1)*1024) : hrow;
            const u16* ctxrow = ctxb + ctx_off;
            f32x4 air = {}, aiz = {}, ain = {}, ahr = {}, ahz = {}, ahn = {};
            for(int k0 = 0; k0 < 1024; k0 += 32){
                short8 a = ald_s8(selrow + k0);
                air = MFMA(a, *(const short8*)(g_wr + k0), air);
                aiz = MFMA(a, *(const short8*)(g_wz + k0), aiz);
                ain = MFMA(a, *(const short8*)(g_wn + k0), ain);
                short8 h = ald_s8(hrow + k0);
                ahr = MFMA(h, *(const short8*)(g_vr + k0), ahr);
                ahz = MFMA(h, *(const short8*)(g_vz + k0), ahz);
                ahn = MFMA(h, *(const short8*)(g_vn + k0), ahn);
            }
            for(int k0 = 0; k0 < 1024; k0 += 32){
                short8 a = ald_s8(ctxrow + k0);
                air = MFMA(a, *(const short8*)(g_wr + 1024 + k0), air);
                aiz = MFMA(a, *(const short8*)(g_wz + 1024 + k0), aiz);
                ain = MFMA(a, *(const short8*)(g_wn + 1024 + k0), ain);
            }
            #pragma unroll
            for(int r = 0; r < 4; ++r){
                int b = p4_row + r;
                float rg = sigm_(air[r] + bir + ahr[r] + bhr);
                float z  = sigm_(aiz[r] + biz + ahz[r] + bhz);
                float n  = tanh_(ain[r] + bin_ + rg*(ahn[r] + bhn));
                float hn = (1.f - z)*n + z*hold[r];
                hold[r] = hn;
                out[(long)b*kOutB + (long)t*1024 + ucol] = hn;
                u32 mb = (u32)f2b(hn);
                u32 ob = (u32)__shfl_xor((int)mb, 1);
                if(!(l & 1))
                    ast32((u32*)hbn + ((b*1024 + ucol) >> 1), mb | (ob << 16));
            }
        }
        gridbar(cnt, gen);
    }
}

extern "C" void kernel_launch(void* const* d_in, const int* in_sizes, int n_in,
                              void* d_out, int out_size, void* d_ws, size_t ws_size,
                              hipStream_t stream){
    (void)in_sizes; (void)n_in; (void)out_size;
    const float* input    = (const float*)d_in[0];   // [64,256,1024]
    const float* hidden   = (const float*)d_in[1];   // [1024,64]
    const float* enc_outs = (const float*)d_in[2];   // [64,256,1024]
    const int*   lengths  = (const int*)  d_in[3];   // [64]
    const float* W_enc    = (const float*)d_in[4];   // [1024,1024] (K,N)
    const float* W_dec    = (const float*)d_in[5];   // [1024,1024] (K,N)
    const float* v        = (const float*)d_in[6];   // [1024]
    const float* W_ih     = (const float*)d_in[7];   // [3072,2048] (N,K)
    const float* W_hh     = (const float*)d_in[8];   // [3072,1024] (N,K)
    const float* b_ih     = (const float*)d_in[9];
    const float* b_hh     = (const float*)d_in[10];
    float* out = (float*)d_out;                      // [64,256,1024]

    // ---- workspace carve (~118 MB) ----
    char* p = (char*)d_ws;
    auto alloc = [&](size_t bytes){ void* r = (void*)p; p += (bytes + 255) & ~(size_t)255; return r; };
    u16* epb   = (u16*)alloc((size_t)16384*1024*2);   // enc_proj bf16
    u16* inb   = (u16*)alloc((size_t)16384*1024*2);   // input bf16
    u16* encb  = (u16*)alloc((size_t)16384*1024*2);   // encoder_outs bf16
    u16* wihb  = (u16*)alloc((size_t)3072*2048*2);
    u16* whhb  = (u16*)alloc((size_t)3072*1024*2);
    u16* wencT = (u16*)alloc((size_t)1024*1024*2);
    u16* wdecT = (u16*)alloc((size_t)1024*1024*2);
    float* hf0 = (float*)alloc((size_t)64*1024*4);
    u16* hb0   = (u16*)alloc((size_t)64*1024*2);
    u16* hb1   = (u16*)alloc((size_t)64*1024*2);
    float* hWp = (float*)alloc((size_t)4*64*1024*4);  // hW K-split partials
    float* eny = (float*)alloc((size_t)64*256*4);
    u16* ctxb  = (u16*)alloc((size_t)64*1024*2);
    u32* sync  = (u32*)alloc(512);
    if((size_t)(p - (char*)d_ws) > ws_size) return;

    // ---- one-time prep ----
    k_cvt<<<2048, 256, 0, stream>>>(enc_outs, encb, 16384*1024);
    k_cvt<<<2048, 256, 0, stream>>>(input,    inb,  16384*1024);
    k_cvt<<<1024, 256, 0, stream>>>(W_ih,     wihb, 3072*2048);
    k_cvt<<<512,  256, 0, stream>>>(W_hh,     whhb, 3072*1024);
    k_cvt_t<<<dim3(32,32), dim3(32,8), 0, stream>>>(W_enc, wencT, 1024, 1024);
    k_cvt_t<<<dim3(32,32), dim3(32,8), 0, stream>>>(W_dec, wdecT, 1024, 1024);
    k_init<<<256, 256, 0, stream>>>(hidden, input, hf0, hb0, out, sync);
    k_gemm_ep<<<dim3(256,16), 256, 0, stream>>>(encb, wencT, epb);

    // ---- all 255 steps in one persistent kernel ----
    k_steps<<<NBLK, 256, 0, stream>>>(epb, inb, encb, wihb, whhb, wdecT,
                                      b_ih, b_hh, v, lengths,
                                      hWp, eny, ctxb, hf0, hb0, hb1,
                                      out, sync);
}

// Round 9
// 25226.881 us; speedup vs baseline: 1.6619x; 1.1804x over previous
//
#include <hip/hip_runtime.h>
#include <stdint.h>

typedef unsigned short u16;
typedef unsigned int   u32;
typedef unsigned long long u64;
typedef __attribute__((ext_vector_type(8))) short short8;
typedef __attribute__((ext_vector_type(4))) short s16x4;
typedef __attribute__((ext_vector_type(4))) float f32x4;

#define MFMA(a,b,c) __builtin_amdgcn_mfma_f32_16x16x32_bf16((a),(b),(c),0,0,0)
#define NBLK 256
#define SMEM_BYTES (131072 + 4096 + 1024 + 64)   // ep 128K | sB 4K | sA 1K | sRed

static const int kD = 1024;
static const long kOutB = 256*1024;   // per-batch stride in out/input [64,256,1024]

__device__ __forceinline__ float b2f(u16 v){ union{u32 u; float f;} c; c.u = ((u32)v)<<16; return c.f; }
__device__ __forceinline__ u16 f2b(float f){ union{float f; u32 u;} c; c.f = f; u32 r = c.u + 0x7FFFu + ((c.u>>16)&1u); return (u16)(r>>16); }
__device__ __forceinline__ float fexp2(float x){ return __builtin_amdgcn_exp2f(x); }
__device__ __forceinline__ float frcp(float x){ return __builtin_amdgcn_rcpf(x); }
__device__ __forceinline__ float tanh_(float x){ float e = fexp2(x*2.885390081777927f); return 1.f - 2.f*frcp(e+1.f); }
__device__ __forceinline__ float sigm_(float x){ return frcp(1.f + fexp2(-1.4426950408889634f*x)); }

// ---- coherent (L2-bypassing, sc1) accessors for cross-XCD communication data ----
__device__ __forceinline__ u64 ald64(const void* p){
    return __hip_atomic_load((const u64*)p, __ATOMIC_RELAXED, __HIP_MEMORY_SCOPE_AGENT);
}
__device__ __forceinline__ u32 ald32(const void* p){
    return __hip_atomic_load((const u32*)p, __ATOMIC_RELAXED, __HIP_MEMORY_SCOPE_AGENT);
}
__device__ __forceinline__ void ast64(void* p, u64 v){
    __hip_atomic_store((u64*)p, v, __ATOMIC_RELAXED, __HIP_MEMORY_SCOPE_AGENT);
}
__device__ __forceinline__ void ast32(void* p, u32 v){
    __hip_atomic_store((u32*)p, v, __ATOMIC_RELAXED, __HIP_MEMORY_SCOPE_AGENT);
}
__device__ __forceinline__ short8 ald_s8(const u16* p){
    union{ u64 q[2]; short8 v; } u;
    u.q[0] = ald64(p);
    u.q[1] = ald64(p + 4);
    return u.v;
}

// ---- JAX partitionable Threefry-2x32, key(1)=(0,1), ctr=(0,j), fold o0^o1 ----
__device__ __forceinline__ u32 rotl32_(u32 x, int r){ return (x << r) | (x >> (32 - r)); }
__device__ bool tf_bit(u32 j){
    const u32 k0 = 0u, k1 = 1u, k2 = 0x1BD11BDAu ^ 0u ^ 1u;
    const int R0[4] = {13,15,26,6}, R1[4] = {17,29,16,24};
    u32 x0 = 0u, x1 = j;
    x0 += k0; x1 += k1;
    for(int i=0;i<4;i++){ x0 += x1; x1 = rotl32_(x1,R0[i]); x1 ^= x0; }
    x0 += k1; x1 += k2 + 1u;
    for(int i=0;i<4;i++){ x0 += x1; x1 = rotl32_(x1,R1[i]); x1 ^= x0; }
    x0 += k2; x1 += k0 + 2u;
    for(int i=0;i<4;i++){ x0 += x1; x1 = rotl32_(x1,R0[i]); x1 ^= x0; }
    x0 += k0; x1 += k1 + 3u;
    for(int i=0;i<4;i++){ x0 += x1; x1 = rotl32_(x1,R1[i]); x1 ^= x0; }
    x0 += k1; x1 += k2 + 4u;
    for(int i=0;i<4;i++){ x0 += x1; x1 = rotl32_(x1,R0[i]); x1 ^= x0; }
    x0 += k2; x1 += k0 + 5u;
    return (((x0 ^ x1) >> 31) == 0u);
}

// ---- two-level grid barrier: 8 groups x 32 blocks -> global; no cache invalidation ----
// sync layout (u32): [0]=global cnt, [32]=gen, [64 + g*32]=group cnt
__device__ __forceinline__ void gridbar(u32* sync){
    asm volatile("s_waitcnt vmcnt(0)" ::: "memory");   // drain sc1 stores to coherence point
    __syncthreads();
    if(threadIdx.x == 0){
        u32* cnt  = sync;
        u32* gen  = sync + 32;
        u32* gcnt = sync + 64 + (blockIdx.x >> 5)*32;
        u32 g = __hip_atomic_load(gen, __ATOMIC_RELAXED, __HIP_MEMORY_SCOPE_AGENT);
        u32 a = __hip_atomic_fetch_add(gcnt, 1u, __ATOMIC_RELAXED, __HIP_MEMORY_SCOPE_AGENT);
        bool done = false;
        if(a == 31u){
            __hip_atomic_store(gcnt, 0u, __ATOMIC_RELAXED, __HIP_MEMORY_SCOPE_AGENT);
            asm volatile("s_waitcnt vmcnt(0)" ::: "memory");
            u32 b = __hip_atomic_fetch_add(cnt, 1u, __ATOMIC_RELAXED, __HIP_MEMORY_SCOPE_AGENT);
            if(b == 7u){
                __hip_atomic_store(cnt, 0u, __ATOMIC_RELAXED, __HIP_MEMORY_SCOPE_AGENT);
                asm volatile("s_waitcnt vmcnt(0)" ::: "memory");
                __hip_atomic_store(gen, g + 1u, __ATOMIC_RELAXED, __HIP_MEMORY_SCOPE_AGENT);
                done = true;
            }
        }
        if(!done)
            while(__hip_atomic_load(gen, __ATOMIC_RELAXED, __HIP_MEMORY_SCOPE_AGENT) == g)
                __builtin_amdgcn_s_sleep(1);
    }
    __syncthreads();
}

// ---- f32 -> bf16 convert (grid-stride) ----
__global__ void k_cvt(const float* __restrict__ in, u16* __restrict__ out, int n){
    int i = blockIdx.x*blockDim.x + threadIdx.x;
    int st = gridDim.x*blockDim.x;
    for(; i < n; i += st) out[i] = f2b(in[i]);
}

// ---- transpose + convert: in [R][C] f32 -> out [C][R] bf16 ----
__global__ void k_cvt_t(const float* __restrict__ in, u16* __restrict__ out, int R, int C){
    __shared__ float tile[32][33];
    int bx = blockIdx.x, by = blockIdx.y;
    int tx = threadIdx.x, ty = threadIdx.y;   // 32 x 8
    for(int j = 0; j < 32; j += 8) tile[ty+j][tx] = in[(by*32+ty+j)*C + bx*32+tx];
    __syncthreads();
    for(int j = 0; j < 32; j += 8) out[(bx*32+ty+j)*R + by*32+tx] = f2b(tile[tx][ty+j]);
}

// ---- init: h0 (f32 + bf16) from hidden^T; outs[:,0,:] = input row 0; zero sync ----
__global__ void k_init(const float* __restrict__ hidden, const float* __restrict__ input,
                       float* __restrict__ h0f, u16* __restrict__ h0b, float* __restrict__ out,
                       u32* __restrict__ sync){
    int i = blockIdx.x*blockDim.x + threadIdx.x;   // 65536
    int b = i >> 10, d = i & 1023;
    float h = hidden[d*64 + b];
    h0f[i] = h; h0b[i] = f2b(h);
    out[(long)b*kOutB + d] = input[(long)b*kOutB + d];
    if(i < 512) sync[i] = 0u;
}

// ---- enc_proj = encb [16384,1024] @ wencT (N,K) -> epb bf16 (one-time) ----
__global__ __launch_bounds__(256) void k_gemm_ep(const u16* __restrict__ A, const u16* __restrict__ BT,
                                                 u16* __restrict__ Cb){
    int m0 = blockIdx.x*64, n0 = blockIdx.y*64;
    int w = threadIdx.x >> 6, l = threadIdx.x & 63;
    int r0 = l & 15, kh = (l >> 4) * 8;
    const u16* arow = A + (long)(m0 + w*16 + r0)*1024 + kh;
    f32x4 acc[4] = {};
    for(int k0 = 0; k0 < 1024; k0 += 32){
        short8 a = *(const short8*)(arow + k0);
        #pragma unroll
        for(int j = 0; j < 4; ++j){
            short8 b = *(const short8*)(BT + (long)(n0 + j*16 + r0)*1024 + k0 + kh);
            acc[j] = MFMA(a, b, acc[j]);
        }
    }
    int orow = m0 + w*16 + (l>>4)*4;
    int ocol = n0 + (l & 15);
    #pragma unroll
    for(int j = 0; j < 4; ++j)
        #pragma unroll
        for(int r = 0; r < 4; ++r)
            Cb[(long)(orow + r)*1024 + ocol + j*16] = f2b(acc[j][r]);
}

// ================= persistent step kernel: 255 steps, 4 phases/step =================
// LDS: ep slice (128 KB) resident across all steps.
__global__ __launch_bounds__(256, 1) void k_steps(
        const u16* __restrict__ epb, const u16* __restrict__ inb, const u16* __restrict__ encb,
        const u16* __restrict__ wihb, const u16* __restrict__ whhb, const u16* __restrict__ wdecT,
        const float* __restrict__ bih, const float* __restrict__ bhh,
        const float* __restrict__ vv, const int* __restrict__ lengths,
        float* __restrict__ hW, float* __restrict__ eny, u16* __restrict__ ctxb,
        const float* __restrict__ hf0,
        u16* __restrict__ hb0, u16* __restrict__ hb1,
        float* __restrict__ out, u32* __restrict__ sync){
    extern __shared__ char smem[];
    u16*   s_ep = (u16*)smem;                          // [64][1024] bf16 = 128 KB
    float* sB   = (float*)(smem + 131072);             // [1024] f32
    float* sA   = (float*)(smem + 131072 + 4096);      // [256] f32
    float* sRed = (float*)(smem + 131072 + 5120);      // [16] f32

    const int bid = blockIdx.x, tid = threadIdx.x;
    const int w = tid >> 6, l = tid & 63;
    const int r0 = l & 15, kh = (l >> 4) * 8;

    // ---- P2/P3 constants: b = bid>>2, sq = bid&3 ----
    const int p2_b = bid >> 2, p2_sq = bid & 3;
    const int p2_len = lengths[p2_b];
    float rv[16];
    #pragma unroll
    for(int j = 0; j < 16; ++j) rv[j] = vv[l*16 + j];
    const u16* p3_eb = encb + (long)p2_b*262144 + p2_sq*256 + l*4;

    // ---- preload ep slice into LDS (once) ----
    {
        const u16* src = epb + (long)(p2_b*256 + p2_sq*64)*1024;
        for(int i = tid; i < 8192; i += 256)
            *(short8*)(s_ep + i*8) = *(const short8*)(src + i*8);
    }
    __syncthreads();

    // ---- P1 constants (bid < 64): 16 n-cols, full K ----
    const int p1_n0 = bid * 16;
    const u16* p1_brow = wdecT + (long)(p1_n0 + r0)*1024 + kh;
    const long p1_aoff = (long)(w*16 + r0)*1024 + kh;
    const int p1_row = w*16 + (l>>4)*4;
    const int p1_col = p1_n0 + (l & 15);
    // ---- P4 constants (bid < 64): u-cols u0..u0+15 ----
    const int u0 = bid * 16;
    const int ucol = u0 + (l & 15);
    const int p4_row = w*16 + (l>>4)*4;
    const u16 *g_wr=0,*g_wz=0,*g_wn=0,*g_vr=0,*g_vz=0,*g_vn=0;
    long ctx_off=0, h_off=0; const u16* g_in=0;
    float bir=0,biz=0,bin_=0,bhr=0,bhz=0,bhn=0;
    float hold[4] = {0.f,0.f,0.f,0.f};
    if(bid < 64){
        g_wr = wihb + (long)(       u0 + r0)*2048 + kh;
        g_wz = wihb + (long)(1024 + u0 + r0)*2048 + kh;
        g_wn = wihb + (long)(2048 + u0 + r0)*2048 + kh;
        g_vr = whhb + (long)(       u0 + r0)*1024 + kh;
        g_vz = whhb + (long)(1024 + u0 + r0)*1024 + kh;
        g_vn = whhb + (long)(2048 + u0 + r0)*1024 + kh;
        ctx_off = (long)(w*16 + r0)*1024 + kh;
        h_off   = ctx_off;
        g_in    = inb + (long)(w*16 + r0)*kOutB + kh;
        bir = bih[ucol]; biz = bih[1024+ucol]; bin_ = bih[2048+ucol];
        bhr = bhh[ucol]; bhz = bhh[1024+ucol]; bhn  = bhh[2048+ucol];
        #pragma unroll
        for(int r = 0; r < 4; ++r) hold[r] = hf0[(p4_row + r)*1024 + ucol];   // h master in regs
    }

    for(int t = 1; t < 256; ++t){
        const bool odd = (t & 1);
        const u16* hbo = odd ? hb0 : hb1;   // h_{t-1} bf16
        u16*       hbn = odd ? hb1 : hb0;   // h_t bf16
        // ---- P1 (64 blocks): hW[64][1024] = hb @ wdecT, full K ----
        if(bid < 64){
            const u16* arow = hbo + p1_aoff;
            f32x4 acc = {};
            for(int k0 = 0; k0 < 1024; k0 += 32)
                acc = MFMA(ald_s8(arow + k0), *(const short8*)(p1_brow + k0), acc);
            #pragma unroll
            for(int r = 0; r < 4; ++r){
                float mine = acc[r];
                float oth = __shfl_xor(mine, 1);
                if(!(l & 1)){
                    union{ float f[2]; u64 q; } pk; pk.f[0] = mine; pk.f[1] = oth;
                    ast64(hW + (p1_row + r)*1024 + p1_col, pk.q);
                }
            }
        }
        gridbar(sync);
        // ---- P2: energy[b, s-quarter] from LDS ep + sc1 hW ----
        {
            float rh[16];
            const float* hp = hW + p2_b*1024 + l*16;
            #pragma unroll
            for(int j = 0; j < 8; ++j){
                union{ u64 q; float f[2]; } uu; uu.q = ald64(hp + j*2);
                rh[2*j] = uu.f[0]; rh[2*j+1] = uu.f[1];
            }
            const u16* lrow = s_ep + (w*16)*1024 + l*16;
            for(int si = 0; si < 16; ++si){
                int s = p2_sq*64 + w*16 + si;
                short8 q0 = *(const short8*)(lrow + si*1024);
                short8 q1 = *(const short8*)(lrow + si*1024 + 8);
                float acc = 0.f;
                #pragma unroll
                for(int j = 0; j < 8; ++j) acc += rv[j]   * tanh_(b2f((u16)q0[j]) + rh[j]);
                #pragma unroll
                for(int j = 0; j < 8; ++j) acc += rv[8+j] * tanh_(b2f((u16)q1[j]) + rh[8+j]);
                #pragma unroll
                for(int off = 32; off; off >>= 1) acc += __shfl_xor(acc, off);
                if(l == 0){
                    float val = (s < p2_len) ? acc : -1e9f;
                    ast32(eny + p2_b*256 + s, __float_as_uint(val));
                }
            }
        }
        gridbar(sync);
        // ---- P3: softmax + ctx[b, d-quarter]; enc via cached loads (L2-resident slice) ----
        {
            float e = __uint_as_float(ald32(eny + p2_b*256 + tid));
            float m = e;
            #pragma unroll
            for(int off = 32; off; off >>= 1) m = fmaxf(m, __shfl_xor(m, off));
            if((tid & 63) == 0) sRed[tid >> 6] = m;
            __syncthreads();
            m = fmaxf(fmaxf(sRed[0], sRed[1]), fmaxf(sRed[2], sRed[3]));
            float pp = fexp2((e - m)*1.4426950408889634f);
            sA[tid] = pp;
            float sm = pp;
            #pragma unroll
            for(int off = 32; off; off >>= 1) sm += __shfl_xor(sm, off);
            if((tid & 63) == 0) sRed[4 + (tid >> 6)] = sm;
            __syncthreads();
            float inv = 1.f / (sRed[4] + sRed[5] + sRed[6] + sRed[7]);
            float a0=0.f, a1=0.f, a2=0.f, a3=0.f;
            #pragma unroll 4
            for(int si = 0; si < 64; ++si){
                int s = w*64 + si;
                float ps = sA[s];
                s16x4 q = *(const s16x4*)(p3_eb + (long)s*1024);
                a0 += ps*b2f((u16)q[0]); a1 += ps*b2f((u16)q[1]);
                a2 += ps*b2f((u16)q[2]); a3 += ps*b2f((u16)q[3]);
            }
            sB[w*256 + l*4+0] = a0; sB[w*256 + l*4+1] = a1;
            sB[w*256 + l*4+2] = a2; sB[w*256 + l*4+3] = a3;
            __syncthreads();
            float c = (sB[tid] + sB[256+tid] + sB[512+tid] + sB[768+tid]) * inv;
            u32 cb = (u32)f2b(c);
            u32 ob = (u32)__shfl_xor((int)cb, 1);
            if(!(tid & 1))
                ast32((u32*)ctxb + ((p2_b*1024 + p2_sq*256 + tid) >> 1), cb | (ob << 16));
        }
        gridbar(sync);
        // ---- P4: fused GRU (64 blocks); A-panels sc1, weights cached, h master in regs ----
        if(bid < 64){
            bool useTeach = (t == 1) || tf_bit((u32)(t - 1));
            const u16* hrow = hbo + h_off;
            const u16* selrow = useTeach ? (g_in + (long)(t - 1)*1024) : hrow;
            const u16* ctxrow = ctxb + ctx_off;
            f32x4 air = {}, aiz = {}, ain = {}, ahr = {}, ahz = {}, ahn = {};
            for(int k0 = 0; k0 < 1024; k0 += 32){
                short8 a = ald_s8(selrow + k0);
                air = MFMA(a, *(const short8*)(g_wr + k0), air);
                aiz = MFMA(a, *(const short8*)(g_wz + k0), aiz);
                ain = MFMA(a, *(const short8*)(g_wn + k0), ain);
                short8 h = ald_s8(hrow + k0);
                ahr = MFMA(h, *(const short8*)(g_vr + k0), ahr);
                ahz = MFMA(h, *(const short8*)(g_vz + k0), ahz);
                ahn = MFMA(h, *(const short8*)(g_vn + k0), ahn);
            }
            for(int k0 = 0; k0 < 1024; k0 += 32){
                short8 a = ald_s8(ctxrow + k0);
                air = MFMA(a, *(const short8*)(g_wr + 1024 + k0), air);
                aiz = MFMA(a, *(const short8*)(g_wz + 1024 + k0), aiz);
                ain = MFMA(a, *(const short8*)(g_wn + 1024 + k0), ain);
            }
            #pragma unroll
            for(int r = 0; r < 4; ++r){
                int b = p4_row + r;
                float rg = sigm_(air[r] + bir + ahr[r] + bhr);
                float z  = sigm_(aiz[r] + biz + ahz[r] + bhz);
                float n  = tanh_(ain[r] + bin_ + rg*(ahn[r] + bhn));
                float hn = (1.f - z)*n + z*hold[r];
                hold[r] = hn;
                out[(long)b*kOutB + (long)t*1024 + ucol] = hn;
                u32 mb = (u32)f2b(hn);
                u32 ob = (u32)__shfl_xor((int)mb, 1);
                if(!(l & 1))
                    ast32((u32*)hbn + ((b*1024 + ucol) >> 1), mb | (ob << 16));
            }
        }
        gridbar(sync);
    }
}

extern "C" void kernel_launch(void* const* d_in, const int* in_sizes, int n_in,
                              void* d_out, int out_size, void* d_ws, size_t ws_size,
                              hipStream_t stream){
    (void)in_sizes; (void)n_in; (void)out_size;
    const float* input    = (const float*)d_in[0];   // [64,256,1024]
    const float* hidden   = (const float*)d_in[1];   // [1024,64]
    const float* enc_outs = (const float*)d_in[2];   // [64,256,1024]
    const int*   lengths  = (const int*)  d_in[3];   // [64]
    const float* W_enc    = (const float*)d_in[4];   // [1024,1024] (K,N)
    const float* W_dec    = (const float*)d_in[5];   // [1024,1024] (K,N)
    const float* v        = (const float*)d_in[6];   // [1024]
    const float* W_ih     = (const float*)d_in[7];   // [3072,2048] (N,K)
    const float* W_hh     = (const float*)d_in[8];   // [3072,1024] (N,K)
    const float* b_ih     = (const float*)d_in[9];
    const float* b_hh     = (const float*)d_in[10];
    float* out = (float*)d_out;                      // [64,256,1024]

    // ---- workspace carve (~118 MB) ----
    char* p = (char*)d_ws;
    auto alloc = [&](size_t bytes){ void* r = (void*)p; p += (bytes + 255) & ~(size_t)255; return r; };
    u16* epb   = (u16*)alloc((size_t)16384*1024*2);   // enc_proj bf16
    u16* inb   = (u16*)alloc((size_t)16384*1024*2);   // input bf16
    u16* encb  = (u16*)alloc((size_t)16384*1024*2);   // encoder_outs bf16
    u16* wihb  = (u16*)alloc((size_t)3072*2048*2);
    u16* whhb  = (u16*)alloc((size_t)3072*1024*2);
    u16* wencT = (u16*)alloc((size_t)1024*1024*2);
    u16* wdecT = (u16*)alloc((size_t)1024*1024*2);
    float* hf0 = (float*)alloc((size_t)64*1024*4);
    u16* hb0   = (u16*)alloc((size_t)64*1024*2);
    u16* hb1   = (u16*)alloc((size_t)64*1024*2);
    float* hW  = (float*)alloc((size_t)64*1024*4);
    float* eny = (float*)alloc((size_t)64*256*4);
    u16* ctxb  = (u16*)alloc((size_t)64*1024*2);
    u32* sync  = (u32*)alloc(2048);
    if((size_t)(p - (char*)d_ws) > ws_size) return;

    // ---- one-time prep ----
    k_cvt<<<2048, 256, 0, stream>>>(enc_outs, encb, 16384*1024);
    k_cvt<<<2048, 256, 0, stream>>>(input,    inb,  16384*1024);
    k_cvt<<<1024, 256, 0, stream>>>(W_ih,     wihb, 3072*2048);
    k_cvt<<<512,  256, 0, stream>>>(W_hh,     whhb, 3072*1024);
    k_cvt_t<<<dim3(32,32), dim3(32,8), 0, stream>>>(W_enc, wencT, 1024, 1024);
    k_cvt_t<<<dim3(32,32), dim3(32,8), 0, stream>>>(W_dec, wdecT, 1024, 1024);
    k_init<<<256, 256, 0, stream>>>(hidden, input, hf0, hb0, out, sync);
    k_gemm_ep<<<dim3(256,16), 256, 0, stream>>>(encb, wencT, epb);

    // ---- all 255 steps in one persistent kernel (128 KB ep slice in LDS) ----
    hipFuncSetAttribute((const void*)k_steps, hipFuncAttributeMaxDynamicSharedMemorySize, SMEM_BYTES);
    k_steps<<<NBLK, 256, SMEM_BYTES, stream>>>(epb, inb, encb, wihb, whhb, wdecT,
                                               b_ih, b_hh, v, lengths,
                                               hW, eny, ctxb, hf0, hb0, hb1,
                                               out, sync);
}